// Round 8
// baseline (2111.072 us; speedup 1.0000x reference)
//
#include <hip/hip_runtime.h>
#include <hip/hip_bf16.h>
#include <math.h>

// Problem dims
#define B_   16
#define T_   256
#define VIN  32000
#define VOUT 32000
#define DEMB 100
#define H_   256
#define H3   768
#define DFF  1024
#define ROWS (B_*T_)   // 4096

typedef __bf16 bf16;
typedef __bf16 bf16x8 __attribute__((ext_vector_type(8)));
typedef float  f32x4  __attribute__((ext_vector_type(4)));

// ---------------- K0: W2 [DFF][VOUT] f32 -> W2T [VOUT][DFF] bf16 ----------------
__global__ __launch_bounds__(256) void k_w2t(const float* __restrict__ W2, bf16* __restrict__ W2T){
  __shared__ float tile[32][33];
  int bn = blockIdx.x % (VOUT/32);
  int bk = blockIdx.x / (VOUT/32);
  int n0 = bn*32, k0 = bk*32;
  int tx = threadIdx.x & 31, ty = threadIdx.x >> 5;   // 32 x 8
  #pragma unroll
  for (int r = ty; r < 32; r += 8)
    tile[r][tx] = W2[(size_t)(k0+r)*VOUT + n0 + tx];
  __syncthreads();
  #pragma unroll
  for (int r = ty; r < 32; r += 8)
    W2T[(size_t)(n0+r)*DFF + k0 + tx] = (bf16)tile[tx][r];
}

// ---------------- K1: xproj = emb[tokens] @ Wx + b[0]  -> [ROWS][H3] f32 ----------------
__global__ __launch_bounds__(256) void k_embed(const int* __restrict__ tokens, const float* __restrict__ emb,
                                               const float* __restrict__ Wx, const float* __restrict__ b0,
                                               float* __restrict__ xproj){
  __shared__ float e[DEMB];
  int row = blockIdx.x;
  int tid = threadIdx.x;
  int tok = tokens[row];
  if (tid < DEMB) e[tid] = emb[(size_t)tok*DEMB + tid];
  __syncthreads();
  float a0 = b0[tid], a1 = b0[tid+256], a2 = b0[tid+512];
  for (int d = 0; d < DEMB; ++d){
    float ed = e[d];
    const float* w = Wx + (size_t)d*H3;
    a0 += ed * w[tid];
    a1 += ed * w[tid+256];
    a2 += ed * w[tid+512];
  }
  float* o = xproj + (size_t)row*H3;
  o[tid] = a0; o[tid+256] = a1; o[tid+512] = a2;
}

// ---------------- K2 (UNLAUNCHED fallback): GRU fp32, one block per batch.
// Kept as the revert path if k_gru_mfma ever fails absmax; not launched. ----------------
__global__ __launch_bounds__(768) void k_gru(const float* __restrict__ xproj, const float* __restrict__ Wh,
                                             const float* __restrict__ b, float* __restrict__ hseq){
  __shared__ float h[H_];
  __shared__ float rec[H3];
  int batch = blockIdx.x;
  int j = threadIdx.x;
  float brec = b[H3 + j];        // recurrent bias
  if (j < H_) h[j] = 0.f;
  __syncthreads();
  for (int t = 0; t < T_; ++t){
    float acc = brec;
    #pragma unroll 8
    for (int k = 0; k < H_; ++k)
      acc += h[k] * Wh[(size_t)k*H3 + j];
    rec[j] = acc;
    __syncthreads();
    if (j < H_){
      size_t base = ((size_t)batch*T_ + t)*H3;
      float xz = xproj[base + j], xr = xproj[base + 256 + j], xh = xproj[base + 512 + j];
      float z  = 1.f/(1.f + expf(-(xz + rec[j])));
      float r  = 1.f/(1.f + expf(-(xr + rec[256 + j])));
      float hh = tanhf(xh + r*rec[512 + j]);
      float hn = z*h[j] + (1.f - z)*hh;
      h[j] = hn;
      hseq[((size_t)batch*T_ + t)*H_ + j] = hn;
    }
    __syncthreads();
  }
}

// ---------------- K2b (PRIMARY): GRU via MFMA, Wh register-resident as bf16 B-fragments.
// 16 blocks x 512 threads (8 waves, 2/SIMD -> 256 VGPR budget).
// Wave w owns 6 N-tiles (96 cols). Layout assumptions (pinned by refcheck'd m97 GEMM
// convention): B-frag lane -> [col=base+l15][k=kg*8+e]; A k-mapping = kg*8+e (A row
// mapping irrelevant: all A rows = h broadcast); C row 0 = lanes 0-15, reg 0.
// State h kept f32 (h_reg) for gate math; quantized to bf16 only as MFMA input.
__global__ __launch_bounds__(512, 2) void k_gru_mfma(const float* __restrict__ xproj,
                                                     const float* __restrict__ Wh,
                                                     const float* __restrict__ b,
                                                     float* __restrict__ hseq){
  __shared__ float rec[H3];
  __shared__ __align__(16) unsigned short h2b[H_];   // bf16 bits of h
  int batch = blockIdx.x;
  int tid  = threadIdx.x;
  int lane = tid & 63, wave = tid >> 6;     // wave 0..7
  int l15  = lane & 15, kg = lane >> 4;     // kg 0..3
  // Prologue: load this wave's Wh fragments (48 frags = 192 VGPRs), bf16 RTN.
  bf16x8 wh[6][8];
  #pragma unroll
  for (int nt = 0; nt < 6; ++nt){
    int col = wave*96 + nt*16 + l15;
    #pragma unroll
    for (int kt = 0; kt < 8; ++kt){
      bf16x8 f;
      #pragma unroll
      for (int e = 0; e < 8; ++e){
        int k = kt*32 + kg*8 + e;
        f[e] = (bf16)Wh[(size_t)k*H3 + col];
      }
      wh[nt][kt] = f;
    }
  }
  float h_reg = 0.f, bz = 0.f, br = 0.f, bh = 0.f;
  if (tid < H_){
    bz = b[H3 + tid]; br = b[H3 + 256 + tid]; bh = b[H3 + 512 + tid];
    h2b[tid] = 0;
  }
  __syncthreads();
  for (int t = 0; t < T_; ++t){
    float xz = 0.f, xr = 0.f, xh = 0.f;
    if (tid < H_){
      size_t base = ((size_t)batch*T_ + t)*H3;
      xz = xproj[base + tid]; xr = xproj[base + 256 + tid]; xh = xproj[base + 512 + tid];
    }
    f32x4 acc[6] = {};
    #pragma unroll
    for (int kt = 0; kt < 8; ++kt){
      bf16x8 af = *(const bf16x8*)&h2b[kt*32 + kg*8];   // h broadcast within kg-group
      #pragma unroll
      for (int nt = 0; nt < 6; ++nt)
        acc[nt] = __builtin_amdgcn_mfma_f32_16x16x32_bf16(af, wh[nt][kt], acc[nt], 0, 0, 0);
    }
    if (lane < 16){
      #pragma unroll
      for (int nt = 0; nt < 6; ++nt)
        rec[wave*96 + nt*16 + l15] = acc[nt][0];   // C row 0: lanes 0-15, reg 0
    }
    __syncthreads();
    if (tid < H_){
      float z  = 1.f/(1.f + expf(-(xz + rec[tid] + bz)));
      float r  = 1.f/(1.f + expf(-(xr + rec[256 + tid] + br)));
      float hh = tanhf(xh + r*(rec[512 + tid] + bh));
      float hn = z*h_reg + (1.f - z)*hh;
      h_reg = hn;
      hseq[((size_t)batch*T_ + t)*H_ + tid] = hn;
      union { bf16 v; unsigned short u; } cv; cv.v = (bf16)hn;
      h2b[tid] = cv.u;
    }
    __syncthreads();
  }
}

// ---------------- K3: d1 = relu(hseq @ W1 + b1) -> bf16 [ROWS][DFF] ----------------
__global__ __launch_bounds__(256) void k_d1(const float* __restrict__ hseq, const float* __restrict__ W1,
                                            const float* __restrict__ b1, bf16* __restrict__ d1){
  __shared__ float hs[16][H_];
  int r0 = blockIdx.x * 16;
  int tid = threadIdx.x;
  #pragma unroll
  for (int r = 0; r < 16; ++r)
    hs[r][tid] = hseq[(size_t)(r0+r)*H_ + tid];
  __syncthreads();
  int c0 = tid*4;
  f32x4 bi = *(const f32x4*)(b1 + c0);
  f32x4 acc[16];
  #pragma unroll
  for (int r = 0; r < 16; ++r) acc[r] = bi;
  for (int k = 0; k < H_; ++k){
    f32x4 w = *(const f32x4*)(W1 + (size_t)k*DFF + c0);
    #pragma unroll
    for (int r = 0; r < 16; ++r)
      acc[r] += hs[r][k] * w;
  }
  #pragma unroll
  for (int r = 0; r < 16; ++r){
    union { bf16 h[4]; uint2 u; } pk;
    #pragma unroll
    for (int i = 0; i < 4; ++i){
      float f = acc[r][i];
      pk.h[i] = (bf16)(f > 0.f ? f : 0.f);
    }
    *(uint2*)(d1 + (size_t)(r0+r)*DFF + c0) = pk.u;
  }
}

// ---------------- K4: logits = d1 @ W2T^T + b2, bf16 MFMA 128x128 tile (m97 structure).
// SWZ=1: XCD-aware bijective block swizzle (grid 8000 % 8 == 0) — identical math,
// different block->XCD placement. Shadow A/B only; SWZ=0 is the primary and runs last.
template<int SWZ>
__global__ __launch_bounds__(256) void k_gemm_t(const bf16* __restrict__ A, const bf16* __restrict__ Bm,
                                                const float* __restrict__ bias, float* __restrict__ C){
  constexpr int K = DFF;    // 1024
  constexpr int N = VOUT;   // 32000
  constexpr int NWG = (ROWS/128)*(VOUT/128);   // 8000
  __shared__ bf16 As[128*32];
  __shared__ bf16 Bs[128*32];
  int bid = blockIdx.x;
  if (SWZ) bid = (bid & 7)*(NWG/8) + (bid >> 3);   // bijective: 8000 % 8 == 0
  int mt = bid & 31;               // M/128 = 32 (m-fast for B-panel L2 reuse)
  int nt = bid >> 5;               // 0..249
  int m0 = mt*128, n0 = nt*128;
  int tid = threadIdx.x, lane = tid & 63, wave = tid >> 6;
  int wr = wave >> 1, wc = wave & 1;            // 2x2 waves of 64x64
  int l15 = lane & 15, kg = lane >> 4;
  f32x4 acc[4][4] = {};
  for (int kt = 0; kt < K/32; ++kt){
    int k0 = kt*32;
    #pragma unroll
    for (int i = 0; i < 2; ++i){
      int lin = (i*4 + wave)*64 + lane;          // 0..511
      int row = lin >> 2;                        // tile row 0..127
      int sub = (lin & 3)*8;                     // bf16 offset within 64B row
      const bf16* ga = A  + (size_t)(m0+row)*K + k0 + sub;
      const bf16* gb = Bm + (size_t)(n0+row)*K + k0 + sub;
      __builtin_amdgcn_global_load_lds((const __attribute__((address_space(1))) void*)ga,
          (__attribute__((address_space(3))) void*)(As + (size_t)(i*4+wave)*512), 16, 0, 0);
      __builtin_amdgcn_global_load_lds((const __attribute__((address_space(1))) void*)gb,
          (__attribute__((address_space(3))) void*)(Bs + (size_t)(i*4+wave)*512), 16, 0, 0);
    }
    __syncthreads();   // compiler drains vmcnt before s_barrier
    bf16x8 af[4], bfr[4];
    #pragma unroll
    for (int m = 0; m < 4; ++m)
      af[m] = *(const bf16x8*)(As + (wr*64 + m*16 + l15)*32 + kg*8);
    #pragma unroll
    for (int n = 0; n < 4; ++n)
      bfr[n] = *(const bf16x8*)(Bs + (wc*64 + n*16 + l15)*32 + kg*8);
    #pragma unroll
    for (int m = 0; m < 4; ++m)
      #pragma unroll
      for (int n = 0; n < 4; ++n)
        acc[m][n] = __builtin_amdgcn_mfma_f32_16x16x32_bf16(af[m], bfr[n], acc[m][n], 0, 0, 0);
    __syncthreads();
  }
  // epilogue: C/D layout col=lane&15, row=(lane>>4)*4+reg (verified mapping)
  #pragma unroll
  for (int n = 0; n < 4; ++n){
    int col = n0 + wc*64 + n*16 + l15;
    float bc = bias[col];
    #pragma unroll
    for (int m = 0; m < 4; ++m){
      int rbase = m0 + wr*64 + m*16 + kg*4;
      f32x4 v = acc[m][n];
      #pragma unroll
      for (int jj = 0; jj < 4; ++jj)
        C[(size_t)(rbase+jj)*N + col] = v[jj] + bc;
    }
  }
}

// ---------------- K5: in-place row softmax on d_out [ROWS][VOUT] ----------------
__global__ __launch_bounds__(1024) void k_softmax(float* __restrict__ out){
  int row = blockIdx.x;
  float* p = out + (size_t)row*VOUT;
  int tid = threadIdx.x;
  float v[32];
  float mx = -INFINITY;
  #pragma unroll
  for (int w = 0; w < 32; ++w){
    int i = w*1024 + tid;
    float x = (i < VOUT) ? p[i] : -INFINITY;
    v[w] = x;
    mx = fmaxf(mx, x);
  }
  #pragma unroll
  for (int o = 32; o; o >>= 1) mx = fmaxf(mx, __shfl_xor(mx, o, 64));
  __shared__ float red[16];
  int wid = tid >> 6;
  if ((tid & 63) == 0) red[wid] = mx;
  __syncthreads();
  float m_all = red[0];
  #pragma unroll
  for (int w = 1; w < 16; ++w) m_all = fmaxf(m_all, red[w]);
  __syncthreads();
  float s = 0.f;
  #pragma unroll
  for (int w = 0; w < 32; ++w){
    int i = w*1024 + tid;
    if (i < VOUT){
      float e = expf(v[w] - m_all);
      v[w] = e;
      s += e;
    }
  }
  #pragma unroll
  for (int o = 32; o; o >>= 1) s += __shfl_xor(s, o, 64);
  if ((tid & 63) == 0) red[wid] = s;
  __syncthreads();
  float total = 0.f;
  #pragma unroll
  for (int w = 0; w < 16; ++w) total += red[w];
  float inv = 1.f/total;
  #pragma unroll
  for (int w = 0; w < 32; ++w){
    int i = w*1024 + tid;
    if (i < VOUT) p[i] = v[w]*inv;
  }
}

extern "C" void kernel_launch(void* const* d_in, const int* in_sizes, int n_in,
                              void* d_out, int out_size, void* d_ws, size_t ws_size,
                              hipStream_t stream){
  const int*   tokens = (const int*)  d_in[0];
  const float* emb    = (const float*)d_in[1];
  const float* Wx     = (const float*)d_in[2];
  const float* Wh     = (const float*)d_in[3];
  const float* b      = (const float*)d_in[4];
  const float* W1     = (const float*)d_in[5];
  const float* b1     = (const float*)d_in[6];
  const float* W2     = (const float*)d_in[7];
  const float* b2     = (const float*)d_in[8];
  float* out = (float*)d_out;

  char* ws = (char*)d_ws;
  float* xproj = (float*)ws;                                     // 12,582,912 B
  float* hseq  = (float*)(ws + 12582912);                        //  4,194,304 B
  bf16*  d1    = (bf16*) (ws + 12582912 + 4194304);              //  8,388,608 B
  bf16*  w2t   = (bf16*) (ws + 12582912 + 4194304 + 8388608);    // 65,536,000 B
  // total ws use: ~90.7 MB
  (void)in_sizes; (void)n_in; (void)out_size; (void)ws_size;

  k_w2t      <<<dim3((VOUT/32)*(DFF/32)), dim3(256), 0, stream>>>(W2, w2t);
  k_embed    <<<dim3(ROWS),               dim3(256), 0, stream>>>(tokens, emb, Wx, b, xproj);
  k_gru_mfma <<<dim3(B_),                 dim3(512), 0, stream>>>(xproj, Wh, b, hseq);   // PRIMARY GRU
  k_d1       <<<dim3(ROWS/16),            dim3(256), 0, stream>>>(hseq, W1, b1, d1);
  k_gemm_t<1><<<dim3((ROWS/128)*(VOUT/128)), dim3(256), 0, stream>>>(d1, w2t, b2, out);  // shadow A/B (identical math)
  k_gemm_t<0><<<dim3((ROWS/128)*(VOUT/128)), dim3(256), 0, stream>>>(d1, w2t, b2, out);  // PRIMARY (overwrites)
  k_softmax  <<<dim3(ROWS),               dim3(1024), 0, stream>>>(out);
}

// Round 13
// 1510.682 us; speedup vs baseline: 1.3974x; 1.3974x over previous
//
#include <hip/hip_runtime.h>
#include <hip/hip_bf16.h>
#include <math.h>

// Problem dims
#define B_   16
#define T_   256
#define VIN  32000
#define VOUT 32000
#define DEMB 100
#define H_   256
#define H3   768
#define DFF  1024
#define ROWS (B_*T_)   // 4096

typedef __bf16 bf16;
typedef __bf16 bf16x8 __attribute__((ext_vector_type(8)));
typedef float  f32x4  __attribute__((ext_vector_type(4)));
typedef unsigned short u16;
typedef u16 u16x8 __attribute__((ext_vector_type(8)));

// ---------------- K0: W2 [DFF][VOUT] f32 -> W2T [VOUT][DFF] bf16 ----------------
__global__ __launch_bounds__(256) void k_w2t(const float* __restrict__ W2, bf16* __restrict__ W2T){
  __shared__ float tile[32][33];
  int bn = blockIdx.x % (VOUT/32);
  int bk = blockIdx.x / (VOUT/32);
  int n0 = bn*32, k0 = bk*32;
  int tx = threadIdx.x & 31, ty = threadIdx.x >> 5;   // 32 x 8
  #pragma unroll
  for (int r = ty; r < 32; r += 8)
    tile[r][tx] = W2[(size_t)(k0+r)*VOUT + n0 + tx];
  __syncthreads();
  #pragma unroll
  for (int r = ty; r < 32; r += 8)
    W2T[(size_t)(n0+r)*DFF + k0 + tx] = (bf16)tile[tx][r];
}

// ---------------- K1: xproj = emb[tokens] @ Wx + b[0]  -> [ROWS][H3] f32 ----------------
__global__ __launch_bounds__(256) void k_embed(const int* __restrict__ tokens, const float* __restrict__ emb,
                                               const float* __restrict__ Wx, const float* __restrict__ b0,
                                               float* __restrict__ xproj){
  __shared__ float e[DEMB];
  int row = blockIdx.x;
  int tid = threadIdx.x;
  int tok = tokens[row];
  if (tid < DEMB) e[tid] = emb[(size_t)tok*DEMB + tid];
  __syncthreads();
  float a0 = b0[tid], a1 = b0[tid+256], a2 = b0[tid+512];
  for (int d = 0; d < DEMB; ++d){
    float ed = e[d];
    const float* w = Wx + (size_t)d*H3;
    a0 += ed * w[tid];
    a1 += ed * w[tid+256];
    a2 += ed * w[tid+512];
  }
  float* o = xproj + (size_t)row*H3;
  o[tid] = a0; o[tid+256] = a1; o[tid+512] = a2;
}

// ---------------- K2 (UNLAUNCHED fallback): GRU fp32. Revert path only. ----------------
__global__ __launch_bounds__(768) void k_gru(const float* __restrict__ xproj, const float* __restrict__ Wh,
                                             const float* __restrict__ b, float* __restrict__ hseq){
  __shared__ float h[H_];
  __shared__ float rec[H3];
  int batch = blockIdx.x;
  int j = threadIdx.x;
  float brec = b[H3 + j];
  if (j < H_) h[j] = 0.f;
  __syncthreads();
  for (int t = 0; t < T_; ++t){
    float acc = brec;
    #pragma unroll 8
    for (int k = 0; k < H_; ++k)
      acc += h[k] * Wh[(size_t)k*H3 + j];
    rec[j] = acc;
    __syncthreads();
    if (j < H_){
      size_t base = ((size_t)batch*T_ + t)*H3;
      float xz = xproj[base + j], xr = xproj[base + 256 + j], xh = xproj[base + 512 + j];
      float z  = 1.f/(1.f + expf(-(xz + rec[j])));
      float r  = 1.f/(1.f + expf(-(xr + rec[256 + j])));
      float hh = tanhf(xh + r*rec[512 + j]);
      float hn = z*h[j] + (1.f - z)*hh;
      h[j] = hn;
      hseq[((size_t)batch*T_ + t)*H_ + j] = hn;
    }
    __syncthreads();
  }
}

// ---------------- K2b (PRIMARY): GRU via MFMA, Wh register-resident as bf16 B-fragments.
// 16 blocks x 512 threads (8 waves, 2/SIMD -> 256 VGPR budget; offline est ~240-246 used).
// Layout pinned by refcheck'd m97 GEMM convention. Validated round 8: absmax 2.38e-07.
// Gates use __expf (rel ~1e-6, 3 orders below bf16 path error).
__global__ __launch_bounds__(512, 2) void k_gru_mfma(const float* __restrict__ xproj,
                                                     const float* __restrict__ Wh,
                                                     const float* __restrict__ b,
                                                     float* __restrict__ hseq){
  __shared__ float rec[H3];
  __shared__ __align__(16) unsigned short h2b[H_];   // bf16 bits of h
  int batch = blockIdx.x;
  int tid  = threadIdx.x;
  int lane = tid & 63, wave = tid >> 6;     // wave 0..7
  int l15  = lane & 15, kg = lane >> 4;     // kg 0..3
  bf16x8 wh[6][8];
  #pragma unroll
  for (int nt = 0; nt < 6; ++nt){
    int col = wave*96 + nt*16 + l15;
    #pragma unroll
    for (int kt = 0; kt < 8; ++kt){
      bf16x8 f;
      #pragma unroll
      for (int e = 0; e < 8; ++e){
        int k = kt*32 + kg*8 + e;
        f[e] = (bf16)Wh[(size_t)k*H3 + col];
      }
      wh[nt][kt] = f;
    }
  }
  float h_reg = 0.f, bz = 0.f, br = 0.f, bh = 0.f;
  if (tid < H_){
    bz = b[H3 + tid]; br = b[H3 + 256 + tid]; bh = b[H3 + 512 + tid];
    h2b[tid] = 0;
  }
  __syncthreads();
  for (int t = 0; t < T_; ++t){
    float xz = 0.f, xr = 0.f, xh = 0.f;
    if (tid < H_){
      size_t base = ((size_t)batch*T_ + t)*H3;
      xz = xproj[base + tid]; xr = xproj[base + 256 + tid]; xh = xproj[base + 512 + tid];
    }
    f32x4 acc[6] = {};
    #pragma unroll
    for (int kt = 0; kt < 8; ++kt){
      bf16x8 af = *(const bf16x8*)&h2b[kt*32 + kg*8];   // h broadcast within kg-group
      #pragma unroll
      for (int nt = 0; nt < 6; ++nt)
        acc[nt] = __builtin_amdgcn_mfma_f32_16x16x32_bf16(af, wh[nt][kt], acc[nt], 0, 0, 0);
    }
    if (lane < 16){
      #pragma unroll
      for (int nt = 0; nt < 6; ++nt)
        rec[wave*96 + nt*16 + l15] = acc[nt][0];   // C row 0: lanes 0-15, reg 0
    }
    __syncthreads();
    if (tid < H_){
      float z  = 1.f/(1.f + __expf(-(xz + rec[tid] + bz)));
      float r  = 1.f/(1.f + __expf(-(xr + rec[256 + tid] + br)));
      float hh = tanhf(xh + r*(rec[512 + tid] + bh));
      float hn = z*h_reg + (1.f - z)*hh;
      h_reg = hn;
      hseq[((size_t)batch*T_ + t)*H_ + tid] = hn;
      union { bf16 v; unsigned short u; } cv; cv.v = (bf16)hn;
      h2b[tid] = cv.u;
    }
    __syncthreads();
  }
}

// ---------------- K3: d1 = relu(hseq @ W1 + b1) -> bf16 [ROWS][DFF] ----------------
__global__ __launch_bounds__(256) void k_d1(const float* __restrict__ hseq, const float* __restrict__ W1,
                                            const float* __restrict__ b1, bf16* __restrict__ d1){
  __shared__ float hs[16][H_];
  int r0 = blockIdx.x * 16;
  int tid = threadIdx.x;
  #pragma unroll
  for (int r = 0; r < 16; ++r)
    hs[r][tid] = hseq[(size_t)(r0+r)*H_ + tid];
  __syncthreads();
  int c0 = tid*4;
  f32x4 bi = *(const f32x4*)(b1 + c0);
  f32x4 acc[16];
  #pragma unroll
  for (int r = 0; r < 16; ++r) acc[r] = bi;
  for (int k = 0; k < H_; ++k){
    f32x4 w = *(const f32x4*)(W1 + (size_t)k*DFF + c0);
    #pragma unroll
    for (int r = 0; r < 16; ++r)
      acc[r] += hs[r][k] * w;
  }
  #pragma unroll
  for (int r = 0; r < 16; ++r){
    union { bf16 h[4]; uint2 u; } pk;
    #pragma unroll
    for (int i = 0; i < 4; ++i){
      float f = acc[r][i];
      pk.h[i] = (bf16)(f > 0.f ? f : 0.f);
    }
    *(uint2*)(d1 + (size_t)(r0+r)*DFF + c0) = pk.u;
  }
}

// ---------------- K4: logits = d1 @ W2T^T + b2, bf16 MFMA 128x128 tile (m97 structure).
// Templated output: OUT=float writes d_out directly (validated path); OUT=bf16 writes
// the ws logits buffer (halves C-write traffic; prob error contribution ~1.5e-8).
// Round-8 counters: 442 us, MfmaUtil 25.9%, HBM 33%. XCD swizzle A/B: NULL — removed. ----------------
template<typename OUT>
__global__ __launch_bounds__(256) void k_gemm_t(const bf16* __restrict__ A, const bf16* __restrict__ Bm,
                                                const float* __restrict__ bias, OUT* __restrict__ C){
  constexpr int K = DFF;    // 1024
  constexpr int N = VOUT;   // 32000
  __shared__ bf16 As[128*32];
  __shared__ bf16 Bs[128*32];
  int mt = blockIdx.x & 31;        // M/128 = 32 (m-fast for B-panel L2 reuse)
  int nt = blockIdx.x >> 5;        // 0..249
  int m0 = mt*128, n0 = nt*128;
  int tid = threadIdx.x, lane = tid & 63, wave = tid >> 6;
  int wr = wave >> 1, wc = wave & 1;            // 2x2 waves of 64x64
  int l15 = lane & 15, kg = lane >> 4;
  f32x4 acc[4][4] = {};
  for (int kt = 0; kt < K/32; ++kt){
    int k0 = kt*32;
    #pragma unroll
    for (int i = 0; i < 2; ++i){
      int lin = (i*4 + wave)*64 + lane;          // 0..511
      int row = lin >> 2;                        // tile row 0..127
      int sub = (lin & 3)*8;                     // bf16 offset within 64B row
      const bf16* ga = A  + (size_t)(m0+row)*K + k0 + sub;
      const bf16* gb = Bm + (size_t)(n0+row)*K + k0 + sub;
      __builtin_amdgcn_global_load_lds((const __attribute__((address_space(1))) void*)ga,
          (__attribute__((address_space(3))) void*)(As + (size_t)(i*4+wave)*512), 16, 0, 0);
      __builtin_amdgcn_global_load_lds((const __attribute__((address_space(1))) void*)gb,
          (__attribute__((address_space(3))) void*)(Bs + (size_t)(i*4+wave)*512), 16, 0, 0);
    }
    __syncthreads();   // compiler drains vmcnt before s_barrier
    bf16x8 af[4], bfr[4];
    #pragma unroll
    for (int m = 0; m < 4; ++m)
      af[m] = *(const bf16x8*)(As + (wr*64 + m*16 + l15)*32 + kg*8);
    #pragma unroll
    for (int n = 0; n < 4; ++n)
      bfr[n] = *(const bf16x8*)(Bs + (wc*64 + n*16 + l15)*32 + kg*8);
    #pragma unroll
    for (int m = 0; m < 4; ++m)
      #pragma unroll
      for (int n = 0; n < 4; ++n)
        acc[m][n] = __builtin_amdgcn_mfma_f32_16x16x32_bf16(af[m], bfr[n], acc[m][n], 0, 0, 0);
    __syncthreads();
  }
  // epilogue: C/D layout col=lane&15, row=(lane>>4)*4+reg (verified mapping)
  #pragma unroll
  for (int n = 0; n < 4; ++n){
    int col = n0 + wc*64 + n*16 + l15;
    float bc = bias[col];
    #pragma unroll
    for (int m = 0; m < 4; ++m){
      int rbase = m0 + wr*64 + m*16 + kg*4;
      f32x4 v = acc[m][n];
      #pragma unroll
      for (int jj = 0; jj < 4; ++jj)
        C[(size_t)(rbase+jj)*N + col] = (OUT)(v[jj] + bc);
    }
  }
}

// ---------------- K5a: row softmax, f32 in-place on d_out (validated fallback path) ----------------
__global__ __launch_bounds__(1024) void k_softmax(float* __restrict__ out){
  int row = blockIdx.x;
  float* p = out + (size_t)row*VOUT;
  int tid = threadIdx.x;
  f32x4 v[8];
  float mx = -INFINITY;
  #pragma unroll
  for (int w = 0; w < 8; ++w){
    int i = w*1024 + tid;               // float4 index, 8000 total
    if (i < 8000){
      v[w] = *(const f32x4*)(p + (size_t)i*4);
      mx = fmaxf(fmaxf(mx, fmaxf(v[w][0], v[w][1])), fmaxf(v[w][2], v[w][3]));
    }
  }
  #pragma unroll
  for (int o = 32; o; o >>= 1) mx = fmaxf(mx, __shfl_xor(mx, o, 64));
  __shared__ float red[16];
  int wid = tid >> 6;
  if ((tid & 63) == 0) red[wid] = mx;
  __syncthreads();
  float m_all = red[0];
  #pragma unroll
  for (int w = 1; w < 16; ++w) m_all = fmaxf(m_all, red[w]);
  __syncthreads();
  float s = 0.f;
  #pragma unroll
  for (int w = 0; w < 8; ++w){
    int i = w*1024 + tid;
    if (i < 8000){
      f32x4 e;
      #pragma unroll
      for (int j = 0; j < 4; ++j) e[j] = __expf(v[w][j] - m_all);
      v[w] = e;
      s += e[0] + e[1] + e[2] + e[3];
    }
  }
  #pragma unroll
  for (int o = 32; o; o >>= 1) s += __shfl_xor(s, o, 64);
  if ((tid & 63) == 0) red[wid] = s;
  __syncthreads();
  float total = 0.f;
  #pragma unroll
  for (int w = 0; w < 16; ++w) total += red[w];
  float inv = 1.f/total;
  #pragma unroll
  for (int w = 0; w < 8; ++w){
    int i = w*1024 + tid;
    if (i < 8000){
      f32x4 r = v[w];
      #pragma unroll
      for (int j = 0; j < 4; ++j) r[j] *= inv;
      *(f32x4*)(p + (size_t)i*4) = r;
    }
  }
}

// ---------------- K5b: row softmax, bf16 logits in -> f32 probs out.
// 32000 bf16 = 4000 groups of 8 (16B loads); 1024 thr x 4 groups; guards at 4000. ----------------
__global__ __launch_bounds__(1024) void k_softmax_bf(const bf16* __restrict__ lg, float* __restrict__ out){
  int row = blockIdx.x;
  const u16* lp = (const u16*)(lg + (size_t)row*VOUT);
  float* p = out + (size_t)row*VOUT;
  int tid = threadIdx.x;
  float v[32];
  float mx = -INFINITY;
  #pragma unroll
  for (int w = 0; w < 4; ++w){
    int i = w*1024 + tid;               // 8-elem group index, 4000 total
    if (i < 4000){
      u16x8 u = *(const u16x8*)(lp + (size_t)i*8);
      #pragma unroll
      for (int j = 0; j < 8; ++j){
        float f = __uint_as_float(((unsigned int)u[j]) << 16);
        v[w*8+j] = f;
        mx = fmaxf(mx, f);
      }
    }
  }
  #pragma unroll
  for (int o = 32; o; o >>= 1) mx = fmaxf(mx, __shfl_xor(mx, o, 64));
  __shared__ float red[16];
  int wid = tid >> 6;
  if ((tid & 63) == 0) red[wid] = mx;
  __syncthreads();
  float m_all = red[0];
  #pragma unroll
  for (int w = 1; w < 16; ++w) m_all = fmaxf(m_all, red[w]);
  __syncthreads();
  float s = 0.f;
  #pragma unroll
  for (int w = 0; w < 4; ++w){
    int i = w*1024 + tid;
    if (i < 4000){
      #pragma unroll
      for (int j = 0; j < 8; ++j){
        float e = __expf(v[w*8+j] - m_all);
        v[w*8+j] = e;
        s += e;
      }
    }
  }
  #pragma unroll
  for (int o = 32; o; o >>= 1) s += __shfl_xor(s, o, 64);
  if ((tid & 63) == 0) red[wid] = s;
  __syncthreads();
  float total = 0.f;
  #pragma unroll
  for (int w = 0; w < 16; ++w) total += red[w];
  float inv = 1.f/total;
  #pragma unroll
  for (int w = 0; w < 4; ++w){
    int i = w*1024 + tid;
    if (i < 4000){
      f32x4 r0, r1;
      #pragma unroll
      for (int j = 0; j < 4; ++j){ r0[j] = v[w*8+j]*inv; r1[j] = v[w*8+4+j]*inv; }
      *(f32x4*)(p + (size_t)i*8)     = r0;
      *(f32x4*)(p + (size_t)i*8 + 4) = r1;
    }
  }
}

extern "C" void kernel_launch(void* const* d_in, const int* in_sizes, int n_in,
                              void* d_out, int out_size, void* d_ws, size_t ws_size,
                              hipStream_t stream){
  const int*   tokens = (const int*)  d_in[0];
  const float* emb    = (const float*)d_in[1];
  const float* Wx     = (const float*)d_in[2];
  const float* Wh     = (const float*)d_in[3];
  const float* b      = (const float*)d_in[4];
  const float* W1     = (const float*)d_in[5];
  const float* b1     = (const float*)d_in[6];
  const float* W2     = (const float*)d_in[7];
  const float* b2     = (const float*)d_in[8];
  float* out = (float*)d_out;

  char* ws = (char*)d_ws;
  float* xproj = (float*)ws;                                     // 12,582,912 B
  float* hseq  = (float*)(ws + 12582912);                        //  4,194,304 B
  bf16*  d1    = (bf16*) (ws + 16777216);                        //  8,388,608 B
  bf16*  w2t   = (bf16*) (ws + 25165824);                        // 65,536,000 B
  bf16*  lgts  = (bf16*) (ws + 90701824);                        // 262,144,000 B (optional)
  const size_t WS_BF = 90701824ULL + 262144000ULL;               // 352,845,824
  bool use_bf = ws_size >= WS_BF;   // constant per session -> graph-capture safe
  (void)in_sizes; (void)n_in; (void)out_size;

  k_w2t     <<<dim3((VOUT/32)*(DFF/32)), dim3(256), 0, stream>>>(W2, w2t);
  k_embed   <<<dim3(ROWS),               dim3(256), 0, stream>>>(tokens, emb, Wx, b, xproj);
  k_gru_mfma<<<dim3(B_),                 dim3(512), 0, stream>>>(xproj, Wh, b, hseq);
  k_d1      <<<dim3(ROWS/16),            dim3(256), 0, stream>>>(hseq, W1, b1, d1);
  if (use_bf){
    k_gemm_t<bf16> <<<dim3((ROWS/128)*(VOUT/128)), dim3(256), 0, stream>>>(d1, w2t, b2, lgts);
    k_softmax_bf   <<<dim3(ROWS),                  dim3(1024), 0, stream>>>(lgts, out);
  } else {
    k_gemm_t<float><<<dim3((ROWS/128)*(VOUT/128)), dim3(256), 0, stream>>>(d1, w2t, b2, out);
    k_softmax      <<<dim3(ROWS),                  dim3(1024), 0, stream>>>(out);
  }
}